// Round 11
// baseline (423.348 us; speedup 1.0000x reference)
//
#include <hip/hip_runtime.h>
#include <math.h>

#define H_HEADS 8
#define C_DIM   32
#define HC      256
#define F_IN    512
#define NEG_SLOPE 0.2f

typedef __attribute__((ext_vector_type(8))) short    bf16x8;
typedef __attribute__((ext_vector_type(4))) float    f32x4;
typedef __attribute__((ext_vector_type(2))) float    f32x2;

__device__ __forceinline__ short f2bf(float f) {
    union { float f; unsigned u; } v; v.f = f;
    unsigned r = v.u + 0x7FFF + ((v.u >> 16) & 1);   // RNE
    return (short)(r >> 16);
}

// packed fp32->bf16 (RNE), 8 elems in 4 instructions
__device__ __forceinline__ bf16x8 cvt8(float4 a, float4 b) {
    union { bf16x8 v; unsigned u[4]; } r;
    asm("v_cvt_pk_bf16_f32 %0, %1, %2" : "=v"(r.u[0]) : "v"(a.x), "v"(a.y));
    asm("v_cvt_pk_bf16_f32 %0, %1, %2" : "=v"(r.u[1]) : "v"(a.z), "v"(a.w));
    asm("v_cvt_pk_bf16_f32 %0, %1, %2" : "=v"(r.u[2]) : "v"(b.x), "v"(b.y));
    asm("v_cvt_pk_bf16_f32 %0, %1, %2" : "=v"(r.u[3]) : "v"(b.z), "v"(b.w));
    return r.v;
}

__device__ __forceinline__ void gl2lds16(const short* g, short* l) {
    __builtin_amdgcn_global_load_lds(
        (const __attribute__((address_space(1))) void*)g,
        (__attribute__((address_space(3))) void*)l, 16, 0, 0);
}

// ---------------------------------------------------------------------------
// MFMA GEMM + fused epilogue — N-split (64 rows x 128 cols), BK=64, bf16 A.
// Roofline status (r10): dur == (FETCH+WRITE)/2TB/s -> HBM-byte-bound on A.
// A is now pre-converted bf16 (51 MB; second read L3-absorbed).
// ---------------------------------------------------------------------------
#define STAGE(ss, buf) do { \
    const short* g_ = Bf + (size_t)(ss) * 8192 + cb * 4096 + w * 512 + lane * 8; \
    short* l_ = &Bs[buf][((ss) & 1) * 4096 + w * 512 + lane * 8]; \
    gl2lds16(g_, l_); \
    gl2lds16(g_ + 2048, l_ + 2048); \
} while (0)

__global__ __launch_bounds__(256) void gemm_mfma(const short* __restrict__ A16,
    const short* __restrict__ Bf, unsigned char* __restrict__ h8,
    const float* __restrict__ a_s, const float* __restrict__ a_d,
    float* __restrict__ alpha_s, float* __restrict__ alpha_d, int M, int K)
{
    __shared__ short Bs[2][8192];            // 2 x 16 KB (BK=64 x 128 cols)
    __shared__ float Als[256], Ald[256];     // 64 rows x 4 heads

    const int tid  = threadIdx.x;
    const int w    = tid >> 6;
    const int lane = tid & 63;
    const int quad = lane >> 4;
    const int ml   = lane & 15;
    const int cb   = blockIdx.x & 1;         // column half (pair shares A rows)
    const int bm   = (blockIdx.x >> 1) * 64;

    const int rowA = bm + w * 16 + ml;
    const int rowL = rowA < M ? rowA : M - 1;
    const short* Ar = A16 + (size_t)rowL * K + quad * 8;

    f32x4 acc[8];
    #pragma unroll
    for (int nb = 0; nb < 8; ++nb) acc[nb] = (f32x4){0.f, 0.f, 0.f, 0.f};

    const int nph = K >> 6;

    STAGE(0, 0);
    STAGE(1, 0);

    bf16x8 pb0 = *(const bf16x8*)(Ar);
    bf16x8 pb1 = *(const bf16x8*)(Ar + 32);

    for (int p = 0; p < nph; ++p) {
        __syncthreads();

        if (p + 1 < nph) {
            STAGE(2 * p + 2, (p + 1) & 1);
            STAGE(2 * p + 3, (p + 1) & 1);
        }

        bf16x8 af0 = pb0, af1 = pb1;
        if (p + 1 < nph) {
            pb0 = *(const bf16x8*)(Ar + (p + 1) * 64);
            pb1 = *(const bf16x8*)(Ar + (p + 1) * 64 + 32);
        }

        const short* b0 = &Bs[p & 1][lane * 8];
        #pragma unroll
        for (int nb = 0; nb < 8; ++nb) {
            bf16x8 bfr = *(const bf16x8*)(b0 + nb * 512);
            acc[nb] = __builtin_amdgcn_mfma_f32_16x16x32_bf16(af0, bfr, acc[nb], 0, 0, 0);
        }
        const short* b1 = &Bs[p & 1][4096 + lane * 8];
        #pragma unroll
        for (int nb = 0; nb < 8; ++nb) {
            bf16x8 bfr = *(const bf16x8*)(b1 + nb * 512);
            acc[nb] = __builtin_amdgcn_mfma_f32_16x16x32_bf16(af1, bfr, acc[nb], 0, 0, 0);
        }
    }

    // ---- epilogue: fp8 store + fused per-head alpha dots (4 heads/block) ----
    float as_v[8], ad_v[8];
    #pragma unroll
    for (int nb = 0; nb < 8; ++nb) {
        as_v[nb] = a_s[cb * 128 + nb * 16 + ml];
        ad_v[nb] = a_d[cb * 128 + nb * 16 + ml];
    }

    #pragma unroll
    for (int r = 0; r < 4; ++r) {
        const int rl  = w * 16 + quad * 4 + r;
        const int row = bm + rl;

        if (row < M) {
            unsigned char* hrow = h8 + (size_t)row * HC + cb * 128;
            #pragma unroll
            for (int i = 0; i < 4; ++i) {
                int pk = __builtin_amdgcn_cvt_pk_fp8_f32(acc[2 * i][r], acc[2 * i + 1][r], 0, false);
                hrow[(2 * i) * 16 + ml]     = (unsigned char)(pk & 0xFF);
                hrow[(2 * i + 1) * 16 + ml] = (unsigned char)((pk >> 8) & 0xFF);
            }
        }

        float hs[4], hd[4];
        #pragma unroll
        for (int q = 0; q < 4; ++q) {
            hs[q] = acc[2 * q][r] * as_v[2 * q] + acc[2 * q + 1][r] * as_v[2 * q + 1];
            hd[q] = acc[2 * q][r] * ad_v[2 * q] + acc[2 * q + 1][r] * ad_v[2 * q + 1];
        }
        #pragma unroll
        for (int off = 1; off < 16; off <<= 1) {
            #pragma unroll
            for (int q = 0; q < 4; ++q) {
                hs[q] += __shfl_xor(hs[q], off);
                hd[q] += __shfl_xor(hd[q], off);
            }
        }
        if (ml == 0) {
            #pragma unroll
            for (int q = 0; q < 4; ++q) {
                Als[rl * 4 + q] = hs[q];
                Ald[rl * 4 + q] = hd[q];
            }
        }
    }
    __syncthreads();
    {
        int rl = tid >> 2, q = tid & 3;      // 256 = 64 rows x 4 heads
        int row = bm + rl;
        if (row < M) {
            alpha_s[(size_t)row * H_HEADS + cb * 4 + q] = Als[tid];
            alpha_d[(size_t)row * H_HEADS + cb * 4 + q] = Ald[tid];
        }
    }
}

// ---------------------------------------------------------------------------
// CSR build
// ---------------------------------------------------------------------------
__global__ void zero_int(int* __restrict__ p, int n)
{
    int i = blockIdx.x * 256 + threadIdx.x;
    if (i < n) p[i] = 0;
}

__global__ void hist_kernel(const int* __restrict__ ei, int E, int N,
                            int* __restrict__ cnt)
{
    int e = blockIdx.x * 256 + threadIdx.x;
    if (e < E) atomicAdd(&cnt[ei[E + e]], 1);
    else if (e < E + N) atomicAdd(&cnt[e - E], 1);
}

__global__ __launch_bounds__(256) void scan_sum(const int* __restrict__ cnt, int n,
                                                int* __restrict__ chunk_sum)
{
    __shared__ int lds[256];
    int b = blockIdx.x, t = threadIdx.x;
    int base = b * 1024 + t * 4;
    int s = 0;
    #pragma unroll
    for (int j = 0; j < 4; ++j) { int i = base + j; if (i < n) s += cnt[i]; }
    lds[t] = s; __syncthreads();
    for (int off = 128; off > 0; off >>= 1) {
        if (t < off) lds[t] += lds[t + off];
        __syncthreads();
    }
    if (t == 0) chunk_sum[b] = lds[0];
}

// scan_local with inlined chunk-offset reduce (each wave reduces <=64 sums).
__global__ __launch_bounds__(256) void scan_local(const int* __restrict__ cnt, int n,
    const int* __restrict__ chunk_sum, int nch, int* __restrict__ row_ptr)
{
    __shared__ int lds[256];
    int b = blockIdx.x, t = threadIdx.x;
    int lane = t & 63;

    int cs  = (lane < nch) ? chunk_sum[lane] : 0;
    int pre = (lane < b)   ? cs : 0;
    int tot = cs;
    #pragma unroll
    for (int off = 32; off > 0; off >>= 1) {
        pre += __shfl_xor(pre, off);
        tot += __shfl_xor(tot, off);
    }

    int base = b * 1024 + t * 4;
    int v[4]; int s = 0;
    #pragma unroll
    for (int j = 0; j < 4; ++j) { int i = base + j; v[j] = (i < n) ? cnt[i] : 0; s += v[j]; }
    lds[t] = s; __syncthreads();
    for (int off = 1; off < 256; off <<= 1) {
        int u = (t >= off) ? lds[t - off] : 0;
        __syncthreads();
        lds[t] += u;
        __syncthreads();
    }
    int run = lds[t] - s + pre;
    #pragma unroll
    for (int j = 0; j < 4; ++j) {
        int i = base + j;
        if (i < n) row_ptr[i] = run;
        run += v[j];
    }
    if (b == gridDim.x - 1 && t == 0) row_ptr[n] = tot;
}

// Reverse-fill scatter + W repack + x fp32->bf16 conversion, one launch.
// Grid = N*F_IN/8 threads (largest job). Conversion runs right before gemm1
// so xbf is L3-hot; same RNE rounding as the old in-loop conversion.
__global__ void prep_scatter_kernel(const int* __restrict__ ei, int E, int N,
    const int* __restrict__ row_ptr, int* __restrict__ cnt, int* __restrict__ es,
    const float* __restrict__ W1, const float* __restrict__ W2,
    short* __restrict__ Wf1, short* __restrict__ Wf2,
    const float* __restrict__ x, short* __restrict__ xbf, int nx8)
{
    const int NW1 = F_IN * HC;
    const int NW2 = HC * HC;
    int e = blockIdx.x * 256 + threadIdx.x;

    if (e < NW1 + NW2) {
        const float* W; short* Wf; int t;
        if (e < NW1) { W = W1; Wf = Wf1; t = e; }
        else         { W = W2; Wf = Wf2; t = e - NW1; }
        int j  = t & 7;
        int l  = (t >> 3) & 63;
        int nb = (t >> 9) & 15;
        int s  = t >> 13;
        int k  = s * 32 + (l >> 4) * 8 + j;
        int n  = nb * 16 + (l & 15);
        Wf[t] = f2bf(W[(size_t)k * HC + n]);
    }

    if (e < E) {
        int src = ei[e], dst = ei[E + e];
        int pos = row_ptr[dst] + atomicSub(&cnt[dst], 1) - 1;
        es[pos] = src;
    } else if (e < E + N) {
        int sd = e - E;
        int pos = row_ptr[sd] + atomicSub(&cnt[sd], 1) - 1;
        es[pos] = sd;
    }

    if (e < nx8) {
        size_t idx = (size_t)e * 8;
        float4 a = *(const float4*)(x + idx);
        float4 b = *(const float4*)(x + idx + 4);
        *(bf16x8*)(xbf + idx) = cvt8(a, b);
    }
}

// ---------------------------------------------------------------------------
// Aggregation with wcalc FUSED, 4-edges-per-wave layout, 16-edge-deep MLP.
// ---------------------------------------------------------------------------
#define ACC4(word, wgt, base_) do { \
    f32x2 lo_ = __builtin_amdgcn_cvt_pk_f32_fp8((word), false); \
    f32x2 hi_ = __builtin_amdgcn_cvt_pk_f32_fp8((word), true);  \
    acc[(base_) + 0] = fmaf((wgt), lo_[0], acc[(base_) + 0]); \
    acc[(base_) + 1] = fmaf((wgt), lo_[1], acc[(base_) + 1]); \
    acc[(base_) + 2] = fmaf((wgt), hi_[0], acc[(base_) + 2]); \
    acc[(base_) + 3] = fmaf((wgt), hi_[1], acc[(base_) + 3]); \
} while (0)

__device__ __forceinline__ float edge_w(float av, float ad8) {
    float e = av + ad8;
    return __expf(e > 0.f ? e : NEG_SLOPE * e);
}

__global__ __launch_bounds__(256) void agg1_kernel(const unsigned char* __restrict__ h8,
    const float* __restrict__ asb, const float* __restrict__ adb,
    const int* __restrict__ row_ptr, const int* __restrict__ es,
    const float* __restrict__ bias, short* __restrict__ z_bf, int N)
{
    const int l  = threadIdx.x & 63;
    const int i  = blockIdx.x * 4 + (threadIdx.x >> 6);
    if (i >= N) return;
    const int c  = l & 15;      // channels 16c..16c+15
    const int eo = l >> 4;      // edge slot
    const int hh = c >> 1;      // head of this lane's channels
    const float ad8 = adb[(size_t)i * 8 + hh];
    const int beg = row_ptr[i], end = row_ptr[i + 1];

    float acc[16];
    #pragma unroll
    for (int j = 0; j < 16; ++j) acc[j] = 0.f;
    float dsum = 0.f;

    int p = beg;
    for (; p + 15 < end; p += 16) {
        int s_[4]; float a_[4]; uint4 h_[4];
        #pragma unroll
        for (int u = 0; u < 4; ++u) s_[u] = es[p + u * 4 + eo];
        #pragma unroll
        for (int u = 0; u < 4; ++u) a_[u] = asb[(size_t)s_[u] * 8 + hh];
        #pragma unroll
        for (int u = 0; u < 4; ++u) h_[u] = *(const uint4*)(h8 + (size_t)s_[u] * 256 + c * 16);
        #pragma unroll
        for (int u = 0; u < 4; ++u) {
            float w_ = edge_w(a_[u], ad8);
            ACC4(h_[u].x, w_, 0); ACC4(h_[u].y, w_, 4);
            ACC4(h_[u].z, w_, 8); ACC4(h_[u].w, w_, 12);
            dsum += w_;
        }
    }
    for (; p + 7 < end; p += 8) {
        int s0 = es[p + eo], s1 = es[p + 4 + eo];
        float a0 = asb[(size_t)s0 * 8 + hh];
        float a1 = asb[(size_t)s1 * 8 + hh];
        uint4 h0 = *(const uint4*)(h8 + (size_t)s0 * 256 + c * 16);
        uint4 h1 = *(const uint4*)(h8 + (size_t)s1 * 256 + c * 16);
        float w0 = edge_w(a0, ad8);
        float w1 = edge_w(a1, ad8);
        ACC4(h0.x, w0, 0); ACC4(h0.y, w0, 4); ACC4(h0.z, w0, 8); ACC4(h0.w, w0, 12);
        ACC4(h1.x, w1, 0); ACC4(h1.y, w1, 4); ACC4(h1.z, w1, 8); ACC4(h1.w, w1, 12);
        dsum += w0 + w1;
    }
    for (; p < end; p += 4) {
        int pe = p + eo;
        int pc = pe < end ? pe : end - 1;
        int s0 = es[pc];
        float w0 = pe < end ? edge_w(asb[(size_t)s0 * 8 + hh], ad8) : 0.f;
        uint4 h0 = *(const uint4*)(h8 + (size_t)s0 * 256 + c * 16);
        ACC4(h0.x, w0, 0); ACC4(h0.y, w0, 4); ACC4(h0.z, w0, 8); ACC4(h0.w, w0, 12);
        dsum += w0;
    }

    #pragma unroll
    for (int j = 0; j < 16; ++j) {
        acc[j] += __shfl_xor(acc[j], 32);
        acc[j] += __shfl_xor(acc[j], 16);
    }
    dsum += __shfl_xor(dsum, 32);
    dsum += __shfl_xor(dsum, 16);

    float inv = 1.f / (dsum + 1e-16f);
    if (eo == 0) {
        union { short s[16]; bf16x8 v[2]; } zz;
        #pragma unroll
        for (int j = 0; j < 16; ++j) {
            float z = acc[j] * inv + bias[c * 16 + j];
            zz.s[j] = f2bf(z > 0.f ? z : 0.f);
        }
        *(bf16x8*)(z_bf + (size_t)i * HC + c * 16)     = zz.v[0];
        *(bf16x8*)(z_bf + (size_t)i * HC + c * 16 + 8) = zz.v[1];
    }
}

__global__ __launch_bounds__(256) void agg2_kernel(const unsigned char* __restrict__ h8,
    const float* __restrict__ asb, const float* __restrict__ adb,
    const int* __restrict__ row_ptr, const int* __restrict__ es,
    const float* __restrict__ b2, const float* __restrict__ Wp,
    const float* __restrict__ bp, float* __restrict__ out, int N)
{
    const int l  = threadIdx.x & 63;
    const int i  = blockIdx.x * 4 + (threadIdx.x >> 6);
    if (i >= N) return;
    const int c  = l & 15;
    const int eo = l >> 4;
    const int hh = c >> 1;
    const float ad8 = adb[(size_t)i * 8 + hh];
    const int beg = row_ptr[i], end = row_ptr[i + 1];

    float acc[16];
    #pragma unroll
    for (int j = 0; j < 16; ++j) acc[j] = 0.f;
    float dsum = 0.f;

    int p = beg;
    for (; p + 15 < end; p += 16) {
        int s_[4]; float a_[4]; uint4 h_[4];
        #pragma unroll
        for (int u = 0; u < 4; ++u) s_[u] = es[p + u * 4 + eo];
        #pragma unroll
        for (int u = 0; u < 4; ++u) a_[u] = asb[(size_t)s_[u] * 8 + hh];
        #pragma unroll
        for (int u = 0; u < 4; ++u) h_[u] = *(const uint4*)(h8 + (size_t)s_[u] * 256 + c * 16);
        #pragma unroll
        for (int u = 0; u < 4; ++u) {
            float w_ = edge_w(a_[u], ad8);
            ACC4(h_[u].x, w_, 0); ACC4(h_[u].y, w_, 4);
            ACC4(h_[u].z, w_, 8); ACC4(h_[u].w, w_, 12);
            dsum += w_;
        }
    }
    for (; p + 7 < end; p += 8) {
        int s0 = es[p + eo], s1 = es[p + 4 + eo];
        float a0 = asb[(size_t)s0 * 8 + hh];
        float a1 = asb[(size_t)s1 * 8 + hh];
        uint4 h0 = *(const uint4*)(h8 + (size_t)s0 * 256 + c * 16);
        uint4 h1 = *(const uint4*)(h8 + (size_t)s1 * 256 + c * 16);
        float w0 = edge_w(a0, ad8);
        float w1 = edge_w(a1, ad8);
        ACC4(h0.x, w0, 0); ACC4(h0.y, w0, 4); ACC4(h0.z, w0, 8); ACC4(h0.w, w0, 12);
        ACC4(h1.x, w1, 0); ACC4(h1.y, w1, 4); ACC4(h1.z, w1, 8); ACC4(h1.w, w1, 12);
        dsum += w0 + w1;
    }
    for (; p < end; p += 4) {
        int pe = p + eo;
        int pc = pe < end ? pe : end - 1;
        int s0 = es[pc];
        float w0 = pe < end ? edge_w(asb[(size_t)s0 * 8 + hh], ad8) : 0.f;
        uint4 h0 = *(const uint4*)(h8 + (size_t)s0 * 256 + c * 16);
        ACC4(h0.x, w0, 0); ACC4(h0.y, w0, 4); ACC4(h0.z, w0, 8); ACC4(h0.w, w0, 12);
        dsum += w0;
    }

    #pragma unroll
    for (int j = 0; j < 16; ++j) {
        acc[j] += __shfl_xor(acc[j], 32);
        acc[j] += __shfl_xor(acc[j], 16);
    }
    dsum += __shfl_xor(dsum, 32);
    dsum += __shfl_xor(dsum, 16);

    float inv = 1.f / (dsum + 1e-16f);
    const int wb = (c & 1) << 4;     // Wp index base = (16c+j) & 31
    float partial = 0.f;
    #pragma unroll
    for (int j = 0; j < 16; ++j) partial = fmaf(acc[j] * inv, Wp[wb + j], partial);
    if (eo == 0 && c < 2) {
        #pragma unroll
        for (int j = 0; j < 16; ++j) partial += 8.f * b2[c * 16 + j] * Wp[c * 16 + j];
    }
    #pragma unroll
    for (int off = 8; off > 0; off >>= 1) partial += __shfl_xor(partial, off);
    if (l == 0) out[i] = 1.f / (1.f + __expf(-(0.125f * partial + bp[0])));
}

// ---------------------------------------------------------------------------
extern "C" void kernel_launch(void* const* d_in, const int* in_sizes, int n_in,
                              void* d_out, int out_size, void* d_ws, size_t ws_size,
                              hipStream_t stream)
{
    const int*   ei  = (const int*)d_in[0];
    const float* x   = (const float*)d_in[1];
    const float* W1  = (const float*)d_in[2];
    const float* as1 = (const float*)d_in[3];
    const float* ad1 = (const float*)d_in[4];
    const float* b1  = (const float*)d_in[5];
    const float* W2  = (const float*)d_in[6];
    const float* as2 = (const float*)d_in[7];
    const float* ad2 = (const float*)d_in[8];
    const float* b2  = (const float*)d_in[9];
    const float* Wp  = (const float*)d_in[10];
    const float* bp  = (const float*)d_in[11];
    float* out = (float*)d_out;

    const int E = in_sizes[0] / 2;
    const int N = in_sizes[1] / F_IN;
    const int ET = E + N;

    // workspace layout (16B-aligned sections)
    float*         asb = (float*)d_ws;                           // N*8 f32
    float*         adb = asb + (size_t)N * H_HEADS;              // N*8 f32
    unsigned char* h8  = (unsigned char*)(adb + (size_t)N * H_HEADS); // N*256 fp8
    short*         z1b = (short*)(h8 + (size_t)N * HC);          // N*256 bf16
    short*         Wf1 = z1b + (size_t)N * HC;                   // 512*256 bf16
    short*         Wf2 = Wf1 + (size_t)F_IN * HC;                // 256*256 bf16
    short*         xbf = Wf2 + (size_t)HC * HC;                  // N*512 bf16 (x, dies after gemm1)
    int*           es  = (int*)(xbf + (size_t)N * F_IN);         // (E+N) int (src)
    int* cnt       = es + ET;                                    // N
    int* row_ptr   = cnt + N;                                    // N+1
    int* chunk_sum = row_ptr + N + 1;                            // 64

    const int NCH = (N + 1023) / 1024;
    const int MB  = ((N + 63) / 64) * 2;     // stripes x 2 column halves
    const int NB4 = (N + 3) / 4;
    const int NX8 = (N * F_IN) / 8;          // x-conversion threads

    // ---- CSR build + prep ----
    zero_int<<<(N + 255) / 256, 256, 0, stream>>>(cnt, N);
    hist_kernel<<<(ET + 255) / 256, 256, 0, stream>>>(ei, E, N, cnt);
    scan_sum<<<NCH, 256, 0, stream>>>(cnt, N, chunk_sum);
    scan_local<<<NCH, 256, 0, stream>>>(cnt, N, chunk_sum, NCH, row_ptr);
    prep_scatter_kernel<<<(NX8 + 255) / 256, 256, 0, stream>>>(ei, E, N, row_ptr, cnt, es,
                                                               W1, W2, Wf1, Wf2, x, xbf, NX8);

    // ---- Layer 1 ----
    gemm_mfma<<<MB, 256, 0, stream>>>(xbf, Wf1, h8, as1, ad1, asb, adb, N, F_IN);
    agg1_kernel<<<NB4, 256, 0, stream>>>(h8, asb, adb, row_ptr, es, b1, z1b, N);

    // ---- Layer 2 ----
    gemm_mfma<<<MB, 256, 0, stream>>>(z1b, Wf2, h8, as2, ad2, asb, adb, N, HC);
    agg2_kernel<<<NB4, 256, 0, stream>>>(h8, asb, adb, row_ptr, es, b2, Wp, bp, out, N);
}

// Round 12
// 421.755 us; speedup vs baseline: 1.0038x; 1.0038x over previous
//
#include <hip/hip_runtime.h>
#include <math.h>

#define H_HEADS 8
#define C_DIM   32
#define HC      256
#define F_IN    512
#define NEG_SLOPE 0.2f

typedef __attribute__((ext_vector_type(8))) short    bf16x8;
typedef __attribute__((ext_vector_type(4))) float    f32x4;
typedef __attribute__((ext_vector_type(2))) float    f32x2;

__device__ __forceinline__ short f2bf(float f) {
    union { float f; unsigned u; } v; v.f = f;
    unsigned r = v.u + 0x7FFF + ((v.u >> 16) & 1);   // RNE
    return (short)(r >> 16);
}

// packed fp32->bf16 (RNE), 8 elems in 4 instructions
__device__ __forceinline__ bf16x8 cvt8(float4 a, float4 b) {
    union { bf16x8 v; unsigned u[4]; } r;
    asm("v_cvt_pk_bf16_f32 %0, %1, %2" : "=v"(r.u[0]) : "v"(a.x), "v"(a.y));
    asm("v_cvt_pk_bf16_f32 %0, %1, %2" : "=v"(r.u[1]) : "v"(a.z), "v"(a.w));
    asm("v_cvt_pk_bf16_f32 %0, %1, %2" : "=v"(r.u[2]) : "v"(b.x), "v"(b.y));
    asm("v_cvt_pk_bf16_f32 %0, %1, %2" : "=v"(r.u[3]) : "v"(b.z), "v"(b.w));
    return r.v;
}

__device__ __forceinline__ void gl2lds16(const short* g, short* l) {
    __builtin_amdgcn_global_load_lds(
        (const __attribute__((address_space(1))) void*)g,
        (__attribute__((address_space(3))) void*)l, 16, 0, 0);
}

// ---------------------------------------------------------------------------
// MFMA GEMM + fused epilogue — N-split (64 rows x 128 cols per block) with
// BK=64 (r10 champion config, 62 us L1). A fp32, in-register cvt_pk to bf16
// (pre-conversion is a proven dead-end: x has zero reuse, 204 vs 102 MB).
// ---------------------------------------------------------------------------
#define STAGE(ss, buf) do { \
    const short* g_ = Bf + (size_t)(ss) * 8192 + cb * 4096 + w * 512 + lane * 8; \
    short* l_ = &Bs[buf][((ss) & 1) * 4096 + w * 512 + lane * 8]; \
    gl2lds16(g_, l_); \
    gl2lds16(g_ + 2048, l_ + 2048); \
} while (0)

template<bool ABF16>
__global__ __launch_bounds__(256) void gemm_mfma(const void* __restrict__ Aptr,
    const short* __restrict__ Bf, unsigned char* __restrict__ h8,
    const float* __restrict__ a_s, const float* __restrict__ a_d,
    float* __restrict__ alpha_s, float* __restrict__ alpha_d, int M, int K)
{
    __shared__ short Bs[2][8192];            // 2 x 16 KB (BK=64 x 128 cols)
    __shared__ float Als[256], Ald[256];     // 64 rows x 4 heads

    const int tid  = threadIdx.x;
    const int w    = tid >> 6;
    const int lane = tid & 63;
    const int quad = lane >> 4;
    const int ml   = lane & 15;
    const int cb   = blockIdx.x & 1;         // column half (pair shares A rows)
    const int bm   = (blockIdx.x >> 1) * 64;

    const int rowA = bm + w * 16 + ml;
    const int rowL = rowA < M ? rowA : M - 1;
    const size_t aoff = (size_t)rowL * K + quad * 8;
    const float* Ar32 = (const float*)Aptr + aoff;
    const short* Ar16 = (const short*)Aptr + aoff;

    f32x4 acc[8];
    #pragma unroll
    for (int nb = 0; nb < 8; ++nb) acc[nb] = (f32x4){0.f, 0.f, 0.f, 0.f};

    const int nph = K >> 6;

    STAGE(0, 0);
    STAGE(1, 0);

    float4 pf0, pf1, pf2, pf3;
    bf16x8 pb0, pb1;
    if (ABF16) {
        pb0 = *(const bf16x8*)(Ar16);
        pb1 = *(const bf16x8*)(Ar16 + 32);
    } else {
        pf0 = *(const float4*)(Ar32);
        pf1 = *(const float4*)(Ar32 + 4);
        pf2 = *(const float4*)(Ar32 + 32);
        pf3 = *(const float4*)(Ar32 + 36);
    }

    for (int p = 0; p < nph; ++p) {
        __syncthreads();

        if (p + 1 < nph) {
            STAGE(2 * p + 2, (p + 1) & 1);
            STAGE(2 * p + 3, (p + 1) & 1);
        }

        bf16x8 af0, af1;
        if (ABF16) {
            af0 = pb0; af1 = pb1;
            if (p + 1 < nph) {
                pb0 = *(const bf16x8*)(Ar16 + (p + 1) * 64);
                pb1 = *(const bf16x8*)(Ar16 + (p + 1) * 64 + 32);
            }
        } else {
            af0 = cvt8(pf0, pf1);
            af1 = cvt8(pf2, pf3);
            if (p + 1 < nph) {
                pf0 = *(const float4*)(Ar32 + (p + 1) * 64);
                pf1 = *(const float4*)(Ar32 + (p + 1) * 64 + 4);
                pf2 = *(const float4*)(Ar32 + (p + 1) * 64 + 32);
                pf3 = *(const float4*)(Ar32 + (p + 1) * 64 + 36);
            }
        }

        const short* b0 = &Bs[p & 1][lane * 8];
        #pragma unroll
        for (int nb = 0; nb < 8; ++nb) {
            bf16x8 bfr = *(const bf16x8*)(b0 + nb * 512);
            acc[nb] = __builtin_amdgcn_mfma_f32_16x16x32_bf16(af0, bfr, acc[nb], 0, 0, 0);
        }
        const short* b1 = &Bs[p & 1][4096 + lane * 8];
        #pragma unroll
        for (int nb = 0; nb < 8; ++nb) {
            bf16x8 bfr = *(const bf16x8*)(b1 + nb * 512);
            acc[nb] = __builtin_amdgcn_mfma_f32_16x16x32_bf16(af1, bfr, acc[nb], 0, 0, 0);
        }
    }

    // ---- epilogue: fp8 store + fused per-head alpha dots (4 heads/block) ----
    float as_v[8], ad_v[8];
    #pragma unroll
    for (int nb = 0; nb < 8; ++nb) {
        as_v[nb] = a_s[cb * 128 + nb * 16 + ml];
        ad_v[nb] = a_d[cb * 128 + nb * 16 + ml];
    }

    #pragma unroll
    for (int r = 0; r < 4; ++r) {
        const int rl  = w * 16 + quad * 4 + r;
        const int row = bm + rl;

        if (row < M) {
            unsigned char* hrow = h8 + (size_t)row * HC + cb * 128;
            #pragma unroll
            for (int i = 0; i < 4; ++i) {
                int pk = __builtin_amdgcn_cvt_pk_fp8_f32(acc[2 * i][r], acc[2 * i + 1][r], 0, false);
                hrow[(2 * i) * 16 + ml]     = (unsigned char)(pk & 0xFF);
                hrow[(2 * i + 1) * 16 + ml] = (unsigned char)((pk >> 8) & 0xFF);
            }
        }

        float hs[4], hd[4];
        #pragma unroll
        for (int q = 0; q < 4; ++q) {
            hs[q] = acc[2 * q][r] * as_v[2 * q] + acc[2 * q + 1][r] * as_v[2 * q + 1];
            hd[q] = acc[2 * q][r] * ad_v[2 * q] + acc[2 * q + 1][r] * ad_v[2 * q + 1];
        }
        #pragma unroll
        for (int off = 1; off < 16; off <<= 1) {
            #pragma unroll
            for (int q = 0; q < 4; ++q) {
                hs[q] += __shfl_xor(hs[q], off);
                hd[q] += __shfl_xor(hd[q], off);
            }
        }
        if (ml == 0) {
            #pragma unroll
            for (int q = 0; q < 4; ++q) {
                Als[rl * 4 + q] = hs[q];
                Ald[rl * 4 + q] = hd[q];
            }
        }
    }
    __syncthreads();
    {
        int rl = tid >> 2, q = tid & 3;      // 256 = 64 rows x 4 heads
        int row = bm + rl;
        if (row < M) {
            alpha_s[(size_t)row * H_HEADS + cb * 4 + q] = Als[tid];
            alpha_d[(size_t)row * H_HEADS + cb * 4 + q] = Ald[tid];
        }
    }
}

// ---------------------------------------------------------------------------
// CSR build
// ---------------------------------------------------------------------------
__global__ void zero_int(int* __restrict__ p, int n)
{
    int i = blockIdx.x * 256 + threadIdx.x;
    if (i < n) p[i] = 0;
}

__global__ void hist_kernel(const int* __restrict__ ei, int E, int N,
                            int* __restrict__ cnt)
{
    int e = blockIdx.x * 256 + threadIdx.x;
    if (e < E) atomicAdd(&cnt[ei[E + e]], 1);
    else if (e < E + N) atomicAdd(&cnt[e - E], 1);
}

__global__ __launch_bounds__(256) void scan_sum(const int* __restrict__ cnt, int n,
                                                int* __restrict__ chunk_sum)
{
    __shared__ int lds[256];
    int b = blockIdx.x, t = threadIdx.x;
    int base = b * 1024 + t * 4;
    int s = 0;
    #pragma unroll
    for (int j = 0; j < 4; ++j) { int i = base + j; if (i < n) s += cnt[i]; }
    lds[t] = s; __syncthreads();
    for (int off = 128; off > 0; off >>= 1) {
        if (t < off) lds[t] += lds[t + off];
        __syncthreads();
    }
    if (t == 0) chunk_sum[b] = lds[0];
}

// scan_local with inlined chunk-offset reduce (each wave reduces <=64 sums).
__global__ __launch_bounds__(256) void scan_local(const int* __restrict__ cnt, int n,
    const int* __restrict__ chunk_sum, int nch, int* __restrict__ row_ptr)
{
    __shared__ int lds[256];
    int b = blockIdx.x, t = threadIdx.x;
    int lane = t & 63;

    int cs  = (lane < nch) ? chunk_sum[lane] : 0;
    int pre = (lane < b)   ? cs : 0;
    int tot = cs;
    #pragma unroll
    for (int off = 32; off > 0; off >>= 1) {
        pre += __shfl_xor(pre, off);
        tot += __shfl_xor(tot, off);
    }

    int base = b * 1024 + t * 4;
    int v[4]; int s = 0;
    #pragma unroll
    for (int j = 0; j < 4; ++j) { int i = base + j; v[j] = (i < n) ? cnt[i] : 0; s += v[j]; }
    lds[t] = s; __syncthreads();
    for (int off = 1; off < 256; off <<= 1) {
        int u = (t >= off) ? lds[t - off] : 0;
        __syncthreads();
        lds[t] += u;
        __syncthreads();
    }
    int run = lds[t] - s + pre;
    #pragma unroll
    for (int j = 0; j < 4; ++j) {
        int i = base + j;
        if (i < n) row_ptr[i] = run;
        run += v[j];
    }
    if (b == gridDim.x - 1 && t == 0) row_ptr[n] = tot;
}

// Reverse-fill scatter (consumes cnt via atomicSub) FUSED with the W repack.
__global__ void scatter_wfrag_kernel(const int* __restrict__ ei, int E, int N,
    const int* __restrict__ row_ptr, int* __restrict__ cnt, int* __restrict__ es,
    const float* __restrict__ W1, const float* __restrict__ W2,
    short* __restrict__ Wf1, short* __restrict__ Wf2)
{
    const int NW1 = F_IN * HC;
    const int NW2 = HC * HC;
    int e = blockIdx.x * 256 + threadIdx.x;

    if (e < NW1 + NW2) {
        const float* W; short* Wf; int t;
        if (e < NW1) { W = W1; Wf = Wf1; t = e; }
        else         { W = W2; Wf = Wf2; t = e - NW1; }
        int j  = t & 7;
        int l  = (t >> 3) & 63;
        int nb = (t >> 9) & 15;
        int s  = t >> 13;
        int k  = s * 32 + (l >> 4) * 8 + j;
        int n  = nb * 16 + (l & 15);
        Wf[t] = f2bf(W[(size_t)k * HC + n]);
    }

    int src, dst;
    if (e < E)          { src = ei[e]; dst = ei[E + e]; }
    else if (e < E + N) { src = dst = e - E; }
    else return;
    int pos = row_ptr[dst] + atomicSub(&cnt[dst], 1) - 1;
    es[pos] = src;
}

// ---------------------------------------------------------------------------
// Aggregation with wcalc FUSED, 4-edges-per-wave layout, 16-edge-deep MLP
// (4 outstanding h8 row-gathers per lane — r11 indirect evidence ~ -8 us/agg).
// ---------------------------------------------------------------------------
#define ACC4(word, wgt, base_) do { \
    f32x2 lo_ = __builtin_amdgcn_cvt_pk_f32_fp8((word), false); \
    f32x2 hi_ = __builtin_amdgcn_cvt_pk_f32_fp8((word), true);  \
    acc[(base_) + 0] = fmaf((wgt), lo_[0], acc[(base_) + 0]); \
    acc[(base_) + 1] = fmaf((wgt), lo_[1], acc[(base_) + 1]); \
    acc[(base_) + 2] = fmaf((wgt), hi_[0], acc[(base_) + 2]); \
    acc[(base_) + 3] = fmaf((wgt), hi_[1], acc[(base_) + 3]); \
} while (0)

__device__ __forceinline__ float edge_w(float av, float ad8) {
    float e = av + ad8;
    return __expf(e > 0.f ? e : NEG_SLOPE * e);
}

__global__ __launch_bounds__(256) void agg1_kernel(const unsigned char* __restrict__ h8,
    const float* __restrict__ asb, const float* __restrict__ adb,
    const int* __restrict__ row_ptr, const int* __restrict__ es,
    const float* __restrict__ bias, short* __restrict__ z_bf, int N)
{
    const int l  = threadIdx.x & 63;
    const int i  = blockIdx.x * 4 + (threadIdx.x >> 6);
    if (i >= N) return;
    const int c  = l & 15;      // channels 16c..16c+15
    const int eo = l >> 4;      // edge slot
    const int hh = c >> 1;      // head of this lane's channels
    const float ad8 = adb[(size_t)i * 8 + hh];
    const int beg = row_ptr[i], end = row_ptr[i + 1];

    float acc[16];
    #pragma unroll
    for (int j = 0; j < 16; ++j) acc[j] = 0.f;
    float dsum = 0.f;

    int p = beg;
    for (; p + 15 < end; p += 16) {
        int s_[4]; float a_[4]; uint4 h_[4];
        #pragma unroll
        for (int u = 0; u < 4; ++u) s_[u] = es[p + u * 4 + eo];
        #pragma unroll
        for (int u = 0; u < 4; ++u) a_[u] = asb[(size_t)s_[u] * 8 + hh];
        #pragma unroll
        for (int u = 0; u < 4; ++u) h_[u] = *(const uint4*)(h8 + (size_t)s_[u] * 256 + c * 16);
        #pragma unroll
        for (int u = 0; u < 4; ++u) {
            float w_ = edge_w(a_[u], ad8);
            ACC4(h_[u].x, w_, 0); ACC4(h_[u].y, w_, 4);
            ACC4(h_[u].z, w_, 8); ACC4(h_[u].w, w_, 12);
            dsum += w_;
        }
    }
    for (; p + 7 < end; p += 8) {
        int s0 = es[p + eo], s1 = es[p + 4 + eo];
        float a0 = asb[(size_t)s0 * 8 + hh];
        float a1 = asb[(size_t)s1 * 8 + hh];
        uint4 h0 = *(const uint4*)(h8 + (size_t)s0 * 256 + c * 16);
        uint4 h1 = *(const uint4*)(h8 + (size_t)s1 * 256 + c * 16);
        float w0 = edge_w(a0, ad8);
        float w1 = edge_w(a1, ad8);
        ACC4(h0.x, w0, 0); ACC4(h0.y, w0, 4); ACC4(h0.z, w0, 8); ACC4(h0.w, w0, 12);
        ACC4(h1.x, w1, 0); ACC4(h1.y, w1, 4); ACC4(h1.z, w1, 8); ACC4(h1.w, w1, 12);
        dsum += w0 + w1;
    }
    for (; p < end; p += 4) {
        int pe = p + eo;
        int pc = pe < end ? pe : end - 1;
        int s0 = es[pc];
        float w0 = pe < end ? edge_w(asb[(size_t)s0 * 8 + hh], ad8) : 0.f;
        uint4 h0 = *(const uint4*)(h8 + (size_t)s0 * 256 + c * 16);
        ACC4(h0.x, w0, 0); ACC4(h0.y, w0, 4); ACC4(h0.z, w0, 8); ACC4(h0.w, w0, 12);
        dsum += w0;
    }

    #pragma unroll
    for (int j = 0; j < 16; ++j) {
        acc[j] += __shfl_xor(acc[j], 32);
        acc[j] += __shfl_xor(acc[j], 16);
    }
    dsum += __shfl_xor(dsum, 32);
    dsum += __shfl_xor(dsum, 16);

    float inv = 1.f / (dsum + 1e-16f);
    if (eo == 0) {
        union { short s[16]; bf16x8 v[2]; } zz;
        #pragma unroll
        for (int j = 0; j < 16; ++j) {
            float z = acc[j] * inv + bias[c * 16 + j];
            zz.s[j] = f2bf(z > 0.f ? z : 0.f);
        }
        *(bf16x8*)(z_bf + (size_t)i * HC + c * 16)     = zz.v[0];
        *(bf16x8*)(z_bf + (size_t)i * HC + c * 16 + 8) = zz.v[1];
    }
}

__global__ __launch_bounds__(256) void agg2_kernel(const unsigned char* __restrict__ h8,
    const float* __restrict__ asb, const float* __restrict__ adb,
    const int* __restrict__ row_ptr, const int* __restrict__ es,
    const float* __restrict__ b2, const float* __restrict__ Wp,
    const float* __restrict__ bp, float* __restrict__ out, int N)
{
    const int l  = threadIdx.x & 63;
    const int i  = blockIdx.x * 4 + (threadIdx.x >> 6);
    if (i >= N) return;
    const int c  = l & 15;
    const int eo = l >> 4;
    const int hh = c >> 1;
    const float ad8 = adb[(size_t)i * 8 + hh];
    const int beg = row_ptr[i], end = row_ptr[i + 1];

    float acc[16];
    #pragma unroll
    for (int j = 0; j < 16; ++j) acc[j] = 0.f;
    float dsum = 0.f;

    int p = beg;
    for (; p + 15 < end; p += 16) {
        int s_[4]; float a_[4]; uint4 h_[4];
        #pragma unroll
        for (int u = 0; u < 4; ++u) s_[u] = es[p + u * 4 + eo];
        #pragma unroll
        for (int u = 0; u < 4; ++u) a_[u] = asb[(size_t)s_[u] * 8 + hh];
        #pragma unroll
        for (int u = 0; u < 4; ++u) h_[u] = *(const uint4*)(h8 + (size_t)s_[u] * 256 + c * 16);
        #pragma unroll
        for (int u = 0; u < 4; ++u) {
            float w_ = edge_w(a_[u], ad8);
            ACC4(h_[u].x, w_, 0); ACC4(h_[u].y, w_, 4);
            ACC4(h_[u].z, w_, 8); ACC4(h_[u].w, w_, 12);
            dsum += w_;
        }
    }
    for (; p + 7 < end; p += 8) {
        int s0 = es[p + eo], s1 = es[p + 4 + eo];
        float a0 = asb[(size_t)s0 * 8 + hh];
        float a1 = asb[(size_t)s1 * 8 + hh];
        uint4 h0 = *(const uint4*)(h8 + (size_t)s0 * 256 + c * 16);
        uint4 h1 = *(const uint4*)(h8 + (size_t)s1 * 256 + c * 16);
        float w0 = edge_w(a0, ad8);
        float w1 = edge_w(a1, ad8);
        ACC4(h0.x, w0, 0); ACC4(h0.y, w0, 4); ACC4(h0.z, w0, 8); ACC4(h0.w, w0, 12);
        ACC4(h1.x, w1, 0); ACC4(h1.y, w1, 4); ACC4(h1.z, w1, 8); ACC4(h1.w, w1, 12);
        dsum += w0 + w1;
    }
    for (; p < end; p += 4) {
        int pe = p + eo;
        int pc = pe < end ? pe : end - 1;
        int s0 = es[pc];
        float w0 = pe < end ? edge_w(asb[(size_t)s0 * 8 + hh], ad8) : 0.f;
        uint4 h0 = *(const uint4*)(h8 + (size_t)s0 * 256 + c * 16);
        ACC4(h0.x, w0, 0); ACC4(h0.y, w0, 4); ACC4(h0.z, w0, 8); ACC4(h0.w, w0, 12);
        dsum += w0;
    }

    #pragma unroll
    for (int j = 0; j < 16; ++j) {
        acc[j] += __shfl_xor(acc[j], 32);
        acc[j] += __shfl_xor(acc[j], 16);
    }
    dsum += __shfl_xor(dsum, 32);
    dsum += __shfl_xor(dsum, 16);

    float inv = 1.f / (dsum + 1e-16f);
    const int wb = (c & 1) << 4;     // Wp index base = (16c+j) & 31
    float partial = 0.f;
    #pragma unroll
    for (int j = 0; j < 16; ++j) partial = fmaf(acc[j] * inv, Wp[wb + j], partial);
    if (eo == 0 && c < 2) {
        #pragma unroll
        for (int j = 0; j < 16; ++j) partial += 8.f * b2[c * 16 + j] * Wp[c * 16 + j];
    }
    #pragma unroll
    for (int off = 8; off > 0; off >>= 1) partial += __shfl_xor(partial, off);
    if (l == 0) out[i] = 1.f / (1.f + __expf(-(0.125f * partial + bp[0])));
}

// ---------------------------------------------------------------------------
extern "C" void kernel_launch(void* const* d_in, const int* in_sizes, int n_in,
                              void* d_out, int out_size, void* d_ws, size_t ws_size,
                              hipStream_t stream)
{
    const int*   ei  = (const int*)d_in[0];
    const float* x   = (const float*)d_in[1];
    const float* W1  = (const float*)d_in[2];
    const float* as1 = (const float*)d_in[3];
    const float* ad1 = (const float*)d_in[4];
    const float* b1  = (const float*)d_in[5];
    const float* W2  = (const float*)d_in[6];
    const float* as2 = (const float*)d_in[7];
    const float* ad2 = (const float*)d_in[8];
    const float* b2  = (const float*)d_in[9];
    const float* Wp  = (const float*)d_in[10];
    const float* bp  = (const float*)d_in[11];
    float* out = (float*)d_out;

    const int E = in_sizes[0] / 2;
    const int N = in_sizes[1] / F_IN;
    const int ET = E + N;

    // workspace layout (16B-aligned sections)
    float*         asb = (float*)d_ws;                           // N*8 f32
    float*         adb = asb + (size_t)N * H_HEADS;              // N*8 f32
    unsigned char* h8  = (unsigned char*)(adb + (size_t)N * H_HEADS); // N*256 fp8
    short*         z1b = (short*)(h8 + (size_t)N * HC);          // N*256 bf16
    short*         Wf1 = z1b + (size_t)N * HC;                   // 512*256 bf16
    short*         Wf2 = Wf1 + (size_t)F_IN * HC;                // 256*256 bf16
    int*           es  = (int*)(Wf2 + (size_t)HC * HC);          // (E+N) int (src)
    int* cnt       = es + ET;                                    // N
    int* row_ptr   = cnt + N;                                    // N+1
    int* chunk_sum = row_ptr + N + 1;                            // 64

    const int NCH = (N + 1023) / 1024;
    const int MB  = ((N + 63) / 64) * 2;     // stripes x 2 column halves
    const int NB4 = (N + 3) / 4;

    // ---- CSR build ----
    zero_int<<<(N + 255) / 256, 256, 0, stream>>>(cnt, N);
    hist_kernel<<<(ET + 255) / 256, 256, 0, stream>>>(ei, E, N, cnt);
    scan_sum<<<NCH, 256, 0, stream>>>(cnt, N, chunk_sum);
    scan_local<<<NCH, 256, 0, stream>>>(cnt, N, chunk_sum, NCH, row_ptr);
    scatter_wfrag_kernel<<<(ET + 255) / 256, 256, 0, stream>>>(ei, E, N, row_ptr, cnt, es,
                                                               W1, W2, Wf1, Wf2);

    // ---- Layer 1 ----
    gemm_mfma<false><<<MB, 256, 0, stream>>>(x, Wf1, h8, as1, ad1, asb, adb, N, F_IN);
    agg1_kernel<<<NB4, 256, 0, stream>>>(h8, asb, adb, row_ptr, es, b1, z1b, N);

    // ---- Layer 2 ----
    gemm_mfma<true><<<MB, 256, 0, stream>>>(z1b, Wf2, h8, as2, ad2, asb, adb, N, HC);
    agg2_kernel<<<NB4, 256, 0, stream>>>(h8, asb, adb, row_ptr, es, b2, Wp, bp, out, N);
}